// Round 2
// baseline (791.302 us; speedup 1.0000x reference)
//
#include <hip/hip_runtime.h>
#include <math.h>

// SwitchMOE: B=8,T=2048,D=1024,F=4096,E=16 ; capacity=1280, K=13
// Memory-bound: W1+W2 streaming = 536 MB dominates (~85us at 6.3 TB/s).
// R2: fused expert (E1+E2 in one launch via f-chunk split + atomic acc),
// no memsets, 5 dispatches total.

#define TOKENS 16384
#define DD     1024
#define FF     4096
#define EE     16
#define CAP    1280
#define KMAX   13
#define NBLK   256   // router/keep blocks, 64 tokens each
#define FCH    128   // f-chunk width in fused expert
#define NCH    (FF / FCH)   // 32 chunks per expert

// ---------------------------------------------------------------- router ----
// block = 256 thr (4 waves), 64 contiguous tokens per block.
// Each wave processes 4 tokens at a time: x in registers, Wr staged in LDS in
// 16KB chunks (j-loop), 64 accumulators, 6-level shfl_xor butterfly reduce.
__global__ __launch_bounds__(256) void router_kernel(
    const float* __restrict__ x, const float* __restrict__ Wr,
    int* __restrict__ top1, float* __restrict__ top1p,
    int* __restrict__ blockhist, float* __restrict__ blockpsum)
{
    __shared__ float wrj[EE * 256];   // 16 KB: Wr[:, j*256:(j+1)*256] as float4
    __shared__ float p_acc[EE];
    __shared__ int   hist[EE];

    const int tid  = threadIdx.x;
    const int wave = tid >> 6;
    const int lane = tid & 63;
    const int blk  = blockIdx.x;

    if (tid < EE) { p_acc[tid] = 0.0f; hist[tid] = 0; }

    for (int it = 0; it < 4; ++it) {
        const int tbase = blk * 64 + wave * 16 + it * 4;

        float4 xr[4][4];
        #pragma unroll
        for (int t = 0; t < 4; ++t) {
            const float4* xp = (const float4*)(x + (size_t)(tbase + t) * DD);
            #pragma unroll
            for (int j = 0; j < 4; ++j) xr[t][j] = xp[j * 64 + lane];
        }

        float acc[4][EE];
        #pragma unroll
        for (int t = 0; t < 4; ++t)
            #pragma unroll
            for (int e = 0; e < EE; ++e) acc[t][e] = 0.0f;

        for (int j = 0; j < 4; ++j) {
            __syncthreads();   // protect previous chunk readers
            #pragma unroll
            for (int k = 0; k < 4; ++k) {
                int i = tid + k * 256;            // float4 index in [0,1024)
                int e = i >> 6, c = i & 63;
                ((float4*)wrj)[i] = ((const float4*)Wr)[e * 256 + j * 64 + c];
            }
            __syncthreads();
            #pragma unroll
            for (int e = 0; e < EE; ++e) {
                float4 w = ((const float4*)(wrj + e * 256))[lane];
                #pragma unroll
                for (int t = 0; t < 4; ++t) {
                    acc[t][e] += xr[t][j].x * w.x + xr[t][j].y * w.y
                               + xr[t][j].z * w.z + xr[t][j].w * w.w;
                }
            }
        }

        // butterfly reduce: every lane ends with all totals
        #pragma unroll
        for (int t = 0; t < 4; ++t)
            #pragma unroll
            for (int e = 0; e < EE; ++e) {
                float v = acc[t][e];
                v += __shfl_xor(v, 32);
                v += __shfl_xor(v, 16);
                v += __shfl_xor(v, 8);
                v += __shfl_xor(v, 4);
                v += __shfl_xor(v, 2);
                v += __shfl_xor(v, 1);
                acc[t][e] = v;
            }

        if (lane < 4) {
            // select this lane's token logits without dynamic reg indexing
            float lg[EE];
            #pragma unroll
            for (int e = 0; e < EE; ++e) {
                float v = acc[3][e];
                if (lane == 2) v = acc[2][e];
                if (lane == 1) v = acc[1][e];
                if (lane == 0) v = acc[0][e];
                lg[e] = v;
            }
            const int gt = tbase + lane;
            float mx = lg[0]; int bi = 0;
            #pragma unroll
            for (int e = 1; e < EE; ++e)
                if (lg[e] > mx) { mx = lg[e]; bi = e; }   // first-max like argmax
            float pr[EE];
            float s = 0.0f;
            #pragma unroll
            for (int e = 0; e < EE; ++e) { pr[e] = expf(lg[e] - mx); s += pr[e]; }
            const float inv = 1.0f / s;
            top1[gt]  = bi;
            top1p[gt] = inv;                 // = exp(0)/s = max prob
            #pragma unroll
            for (int e = 0; e < EE; ++e) atomicAdd(&p_acc[e], pr[e] * inv);
            atomicAdd(&hist[bi], 1);
        }
    }
    __syncthreads();
    if (tid < EE) {
        blockhist[blk * EE + tid] = hist[tid];
        blockpsum[blk * EE + tid] = p_acc[tid];
    }
}

// ------------------------------------------------------------------ scan ----
// single block: exclusive prefix of blockhist over 256 blocks per expert,
// n_kept, token-0 fill multiplicity, lb_loss (reducing blockpsum).
__global__ __launch_bounds__(256) void scan_kernel(
    const int* __restrict__ blockhist, const float* __restrict__ blockpsum,
    int* __restrict__ base, int* __restrict__ nkept,
    const int* __restrict__ top1, float* __restrict__ mult0,
    float* __restrict__ lb_out)
{
    __shared__ int   hist_l[NBLK * EE];   // 16 KB
    __shared__ int   gsum[EE * 16];
    __shared__ float fps[EE * 16];
    __shared__ float fp[EE];
    __shared__ int   nk_l[EE];

    const int tid = threadIdx.x;
    for (int i = tid; i < NBLK * EE; i += 256) hist_l[i] = blockhist[i];
    __syncthreads();

    const int e = tid >> 4, g = tid & 15;   // 16 experts x 16 groups of 16 blocks
    int s = 0;
    float sp = 0.0f;
    for (int b = g * 16; b < g * 16 + 16; ++b) {
        s  += hist_l[b * EE + e];
        sp += blockpsum[b * EE + e];
    }
    gsum[e * 16 + g] = s;
    fps[e * 16 + g]  = sp;
    __syncthreads();

    int pre = 0;
    for (int g2 = 0; g2 < g; ++g2) pre += gsum[e * 16 + g2];
    int run = pre;
    for (int b = g * 16; b < g * 16 + 16; ++b) {
        base[b * EE + e] = run;
        run += hist_l[b * EE + e];
    }
    if (g == 15) {
        const int c = run;                      // total count for expert e
        const int nk = (c > 0) ? ((c - 1) / CAP + 1) : 0;
        nkept[e] = nk;
        nk_l[e]  = nk;
        float ps = 0.0f;
        for (int g2 = 0; g2 < 16; ++g2) ps += fps[e * 16 + g2];
        fp[e] = ((float)c / (float)TOKENS) * (ps / (float)TOKENS);
    }
    __syncthreads();
    if (tid == 0) {
        const int e0 = top1[0];
        mult0[0] = (float)(1 + KMAX - nk_l[e0]);  // token-0 fill multiplicity
        float sum = 0.0f;
        for (int i = 0; i < EE; ++i) sum += fp[i];
        lb_out[0] = (float)EE * sum * 0.01f;
    }
}

// ------------------------------------------------------------------ keep ----
// per 64-token block: within-block rank recount -> kept-slot list, full
// slotmap write (no memset), and zero-init of the atomic acc buffer.
__global__ __launch_bounds__(64) void keep_kernel(
    const int* __restrict__ top1, const float* __restrict__ top1p,
    const int* __restrict__ base, const float* __restrict__ mult0,
    int* __restrict__ kept_tok, float* __restrict__ kept_scale,
    int* __restrict__ slotmap, float* __restrict__ acc)
{
    __shared__ int t1[64];
    const int tid = threadIdx.x;
    const int blk = blockIdx.x;
    const int gt  = blk * 64 + tid;
    const int e   = top1[gt];
    t1[tid] = e;
    __syncthreads();
    int r = 0;
    for (int i = 0; i < tid; ++i) r += (t1[i] == e) ? 1 : 0;
    const int rank = base[blk * EE + e] + r;
    int sm = -1;
    if (rank % CAP == 0) {
        const int slot = rank / CAP;            // kth kept token has rank k*CAP
        sm = e * KMAX + slot;
        kept_tok[sm] = gt;
        float sc = top1p[gt];
        if (gt == 0) sc *= mult0[0];            // fold fill-slot multiplicity
        kept_scale[sm] = sc;
    }
    slotmap[gt] = sm;
    // zero acc: EE*KMAX*DD = 212992 floats = 53248 float4, grid-stride
    float4* a4 = (float4*)acc;
    for (int i = gt; i < EE * KMAX * DD / 4; i += NBLK * 64)
        a4[i] = make_float4(0.0f, 0.0f, 0.0f, 0.0f);
}

// --------------------------------------------------------- fused expert -----
// block = (expert e, f-chunk of 128). Phase 1: h[s][cf] = gelu(W1 row . x)
// into LDS. Phase 2: partial eo over this chunk's f range, atomicAdd into acc.
// Streams all of W1+W2 (536 MB) in ONE launch, no global barrier.
__global__ __launch_bounds__(256) void expert_fused_kernel(
    const float* __restrict__ x, const float* __restrict__ W1,
    const float* __restrict__ b1, const float* __restrict__ W2,
    const int* __restrict__ nkept, const int* __restrict__ kept_tok,
    float* __restrict__ acc)
{
    const int blk = blockIdx.x;       // 512 = EE * NCH
    const int e   = blk >> 5;
    const int ch  = blk & (NCH - 1);
    const int f0  = ch * FCH;
    const int ne  = nkept[e];
    if (ne == 0) return;

    __shared__ float h_l[KMAX * FCH];  // 6.6 KB

    const int wave = threadIdx.x >> 6;
    const int lane = threadIdx.x & 63;

    // ---- phase 1: 128 f-rows, wave w handles rows [w*32, w*32+32)
    for (int r = 0; r < 32; ++r) {
        const int cf = wave * 32 + r;
        const int f  = f0 + cf;
        const float4* wrow = (const float4*)(W1 + ((size_t)e * FF + f) * DD);
        const float4 w0 = wrow[lane];
        const float4 w1 = wrow[64 + lane];
        const float4 w2 = wrow[128 + lane];
        const float4 w3 = wrow[192 + lane];
        for (int s = 0; s < ne; ++s) {
            const int t = kept_tok[e * KMAX + s];
            const float4* xp = (const float4*)(x + (size_t)t * DD);
            const float4 x0 = xp[lane];
            const float4 x1 = xp[64 + lane];
            const float4 x2 = xp[128 + lane];
            const float4 x3 = xp[192 + lane];
            float d = w0.x*x0.x + w0.y*x0.y + w0.z*x0.z + w0.w*x0.w
                    + w1.x*x1.x + w1.y*x1.y + w1.z*x1.z + w1.w*x1.w
                    + w2.x*x2.x + w2.y*x2.y + w2.z*x2.z + w2.w*x2.w
                    + w3.x*x3.x + w3.y*x3.y + w3.z*x3.z + w3.w*x3.w;
            d += __shfl_xor(d, 32);
            d += __shfl_xor(d, 16);
            d += __shfl_xor(d, 8);
            d += __shfl_xor(d, 4);
            d += __shfl_xor(d, 2);
            d += __shfl_xor(d, 1);
            if (lane == 0) {
                const float v = d + b1[e * FF + f];
                // exact gelu: 0.5*v*(1+erf(v/sqrt(2)))
                h_l[s * FCH + cf] =
                    0.5f * v * (1.0f + erff(v * 0.70710678118654752440f));
            }
        }
    }
    __syncthreads();

    // ---- phase 2: 1024 d-rows, wave w handles d in [w*256, w*256+256).
    // lane l covers f = f0 + 2l (float2), 6-level butterfly per (d,s).
    for (int i = 0; i < 256; ++i) {
        const int d = wave * 256 + i;
        const float2 w = ((const float2*)(W2 + ((size_t)e * DD + d) * FF + f0))[lane];
        for (int s = 0; s < ne; ++s) {
            const float2 hv = ((const float2*)(h_l + s * FCH))[lane];
            float v = w.x * hv.x + w.y * hv.y;
            v += __shfl_xor(v, 32);
            v += __shfl_xor(v, 16);
            v += __shfl_xor(v, 8);
            v += __shfl_xor(v, 4);
            v += __shfl_xor(v, 2);
            v += __shfl_xor(v, 1);
            if (lane == 0)
                atomicAdd(&acc[((size_t)e * KMAX + s) * DD + d], v);
        }
    }
}

// ---------------------------------------------------------------- expand ----
// single coalesced pass writing the full output: 0 for non-kept tokens,
// scale*(acc + b2) for kept rows. Also the only reader of acc.
__global__ __launch_bounds__(256) void expand_kernel(
    const float* __restrict__ acc, const float* __restrict__ kept_scale,
    const float* __restrict__ b2, const int* __restrict__ slotmap,
    float* __restrict__ out)
{
    const int nf4 = TOKENS * DD / 4;            // 4194304 float4
    int idx = blockIdx.x * 256 + threadIdx.x;
    const int stride = 4096 * 256;
    for (; idx < nf4; idx += stride) {
        const int t    = idx >> 8;              // 256 float4 per token
        const int slot = slotmap[t];
        float4 v = make_float4(0.0f, 0.0f, 0.0f, 0.0f);
        if (slot >= 0) {
            const int e = slot / KMAX;
            const float sc = kept_scale[slot];
            const float4 a  = ((const float4*)acc)[slot * 256 + (idx & 255)];
            const float4 bb = ((const float4*)b2)[e * 256 + (idx & 255)];
            v = make_float4(sc * (a.x + bb.x), sc * (a.y + bb.y),
                            sc * (a.z + bb.z), sc * (a.w + bb.w));
        }
        ((float4*)out)[idx] = v;
    }
}

// -------------------------------------------------------------- launcher ----
extern "C" void kernel_launch(void* const* d_in, const int* in_sizes, int n_in,
                              void* d_out, int out_size, void* d_ws, size_t ws_size,
                              hipStream_t stream) {
    const float* x  = (const float*)d_in[0];
    const float* Wr = (const float*)d_in[1];
    const float* W1 = (const float*)d_in[2];
    const float* b1 = (const float*)d_in[3];
    const float* W2 = (const float*)d_in[4];
    const float* b2 = (const float*)d_in[5];
    float* out = (float*)d_out;

    char* p = (char*)d_ws;
    int*   top1       = (int*)p;    p += (size_t)TOKENS * 4;
    float* top1p      = (float*)p;  p += (size_t)TOKENS * 4;
    int*   slotmap    = (int*)p;    p += (size_t)TOKENS * 4;
    int*   blockhist  = (int*)p;    p += (size_t)NBLK * EE * 4;
    float* blockpsum  = (float*)p;  p += (size_t)NBLK * EE * 4;
    int*   base       = (int*)p;    p += (size_t)NBLK * EE * 4;
    int*   nkept      = (int*)p;    p += 256;
    float* mult0      = (float*)p;  p += 256;
    int*   kept_tok   = (int*)p;    p += 1024;   // EE*KMAX ints, padded
    float* kept_scale = (float*)p;  p += 1024;
    float* acc        = (float*)p;  p += (size_t)EE * KMAX * DD * 4;
    (void)ws_size; (void)in_sizes; (void)n_in;

    router_kernel<<<NBLK, 256, 0, stream>>>(x, Wr, top1, top1p,
                                            blockhist, blockpsum);
    scan_kernel<<<1, 256, 0, stream>>>(blockhist, blockpsum, base, nkept,
                                       top1, mult0, out + (size_t)out_size - 1);
    keep_kernel<<<NBLK, 64, 0, stream>>>(top1, top1p, base, mult0,
                                         kept_tok, kept_scale, slotmap, acc);
    expert_fused_kernel<<<EE * NCH, 256, 0, stream>>>(x, W1, b1, W2,
                                                      nkept, kept_tok, acc);
    expand_kernel<<<4096, 256, 0, stream>>>(acc, kept_scale, b2, slotmap, out);
}

// Round 3
// 674.836 us; speedup vs baseline: 1.1726x; 1.1726x over previous
//
#include <hip/hip_runtime.h>
#include <math.h>

// SwitchMOE: B=8,T=2048,D=1024,F=4096,E=16 ; capacity=1280, K=13
// R3: split E1/E2 (R2 fusion was latency-bound: 128-f chunks paid a 6-level
// bpermute butterfly per 512B of W2). E2 now amortizes ONE butterfly per
// 16KB W2 row with h staged in LDS. No atomics, no memsets, 6 dispatches.

#define TOKENS 16384
#define DD     1024
#define FF     4096
#define EE     16
#define CAP    1280
#define KMAX   13
#define NBLK   256   // router/keep blocks, 64 tokens each

// ---------------------------------------------------------------- router ----
// block = 256 thr (4 waves), 64 contiguous tokens per block.
// Each wave processes 4 tokens at a time: x in registers, Wr staged in LDS in
// 16KB chunks (j-loop), 64 accumulators, 6-level shfl_xor butterfly reduce.
__global__ __launch_bounds__(256) void router_kernel(
    const float* __restrict__ x, const float* __restrict__ Wr,
    int* __restrict__ top1, float* __restrict__ top1p,
    int* __restrict__ blockhist, float* __restrict__ blockpsum)
{
    __shared__ float wrj[EE * 256];   // 16 KB: Wr[:, j*256:(j+1)*256] as float4
    __shared__ float p_acc[EE];
    __shared__ int   hist[EE];

    const int tid  = threadIdx.x;
    const int wave = tid >> 6;
    const int lane = tid & 63;
    const int blk  = blockIdx.x;

    if (tid < EE) { p_acc[tid] = 0.0f; hist[tid] = 0; }

    for (int it = 0; it < 4; ++it) {
        const int tbase = blk * 64 + wave * 16 + it * 4;

        float4 xr[4][4];
        #pragma unroll
        for (int t = 0; t < 4; ++t) {
            const float4* xp = (const float4*)(x + (size_t)(tbase + t) * DD);
            #pragma unroll
            for (int j = 0; j < 4; ++j) xr[t][j] = xp[j * 64 + lane];
        }

        float acc[4][EE];
        #pragma unroll
        for (int t = 0; t < 4; ++t)
            #pragma unroll
            for (int e = 0; e < EE; ++e) acc[t][e] = 0.0f;

        for (int j = 0; j < 4; ++j) {
            __syncthreads();   // protect previous chunk readers
            #pragma unroll
            for (int k = 0; k < 4; ++k) {
                int i = tid + k * 256;            // float4 index in [0,1024)
                int e = i >> 6, c = i & 63;
                ((float4*)wrj)[i] = ((const float4*)Wr)[e * 256 + j * 64 + c];
            }
            __syncthreads();
            #pragma unroll
            for (int e = 0; e < EE; ++e) {
                float4 w = ((const float4*)(wrj + e * 256))[lane];
                #pragma unroll
                for (int t = 0; t < 4; ++t) {
                    acc[t][e] += xr[t][j].x * w.x + xr[t][j].y * w.y
                               + xr[t][j].z * w.z + xr[t][j].w * w.w;
                }
            }
        }

        // butterfly reduce: every lane ends with all totals
        #pragma unroll
        for (int t = 0; t < 4; ++t)
            #pragma unroll
            for (int e = 0; e < EE; ++e) {
                float v = acc[t][e];
                v += __shfl_xor(v, 32);
                v += __shfl_xor(v, 16);
                v += __shfl_xor(v, 8);
                v += __shfl_xor(v, 4);
                v += __shfl_xor(v, 2);
                v += __shfl_xor(v, 1);
                acc[t][e] = v;
            }

        if (lane < 4) {
            // select this lane's token logits without dynamic reg indexing
            float lg[EE];
            #pragma unroll
            for (int e = 0; e < EE; ++e) {
                float v = acc[3][e];
                if (lane == 2) v = acc[2][e];
                if (lane == 1) v = acc[1][e];
                if (lane == 0) v = acc[0][e];
                lg[e] = v;
            }
            const int gt = tbase + lane;
            float mx = lg[0]; int bi = 0;
            #pragma unroll
            for (int e = 1; e < EE; ++e)
                if (lg[e] > mx) { mx = lg[e]; bi = e; }   // first-max like argmax
            float pr[EE];
            float s = 0.0f;
            #pragma unroll
            for (int e = 0; e < EE; ++e) { pr[e] = expf(lg[e] - mx); s += pr[e]; }
            const float inv = 1.0f / s;
            top1[gt]  = bi;
            top1p[gt] = inv;                 // = exp(0)/s = max prob
            #pragma unroll
            for (int e = 0; e < EE; ++e) atomicAdd(&p_acc[e], pr[e] * inv);
            atomicAdd(&hist[bi], 1);
        }
    }
    __syncthreads();
    if (tid < EE) {
        blockhist[blk * EE + tid] = hist[tid];
        blockpsum[blk * EE + tid] = p_acc[tid];
    }
}

// ------------------------------------------------------------------ scan ----
// single block: exclusive prefix of blockhist over 256 blocks per expert,
// n_kept, token-0 fill multiplicity, lb_loss (reducing blockpsum).
__global__ __launch_bounds__(256) void scan_kernel(
    const int* __restrict__ blockhist, const float* __restrict__ blockpsum,
    int* __restrict__ base, int* __restrict__ nkept,
    const int* __restrict__ top1, float* __restrict__ mult0,
    float* __restrict__ lb_out)
{
    __shared__ int   hist_l[NBLK * EE];   // 16 KB
    __shared__ int   gsum[EE * 16];
    __shared__ float fps[EE * 16];
    __shared__ float fp[EE];
    __shared__ int   nk_l[EE];

    const int tid = threadIdx.x;
    for (int i = tid; i < NBLK * EE; i += 256) hist_l[i] = blockhist[i];
    __syncthreads();

    const int e = tid >> 4, g = tid & 15;   // 16 experts x 16 groups of 16 blocks
    int s = 0;
    float sp = 0.0f;
    for (int b = g * 16; b < g * 16 + 16; ++b) {
        s  += hist_l[b * EE + e];
        sp += blockpsum[b * EE + e];
    }
    gsum[e * 16 + g] = s;
    fps[e * 16 + g]  = sp;
    __syncthreads();

    int pre = 0;
    for (int g2 = 0; g2 < g; ++g2) pre += gsum[e * 16 + g2];
    int run = pre;
    for (int b = g * 16; b < g * 16 + 16; ++b) {
        base[b * EE + e] = run;
        run += hist_l[b * EE + e];
    }
    if (g == 15) {
        const int c = run;                      // total count for expert e
        const int nk = (c > 0) ? ((c - 1) / CAP + 1) : 0;
        nkept[e] = nk;
        nk_l[e]  = nk;
        float ps = 0.0f;
        for (int g2 = 0; g2 < 16; ++g2) ps += fps[e * 16 + g2];
        fp[e] = ((float)c / (float)TOKENS) * (ps / (float)TOKENS);
    }
    __syncthreads();
    if (tid == 0) {
        const int e0 = top1[0];
        mult0[0] = (float)(1 + KMAX - nk_l[e0]);  // token-0 fill multiplicity
        float sum = 0.0f;
        for (int i = 0; i < EE; ++i) sum += fp[i];
        lb_out[0] = (float)EE * sum * 0.01f;
    }
}

// ------------------------------------------------------------------ keep ----
// per 64-token block: within-block rank recount -> kept-slot list + full
// slotmap write (no memset needed).
__global__ __launch_bounds__(64) void keep_kernel(
    const int* __restrict__ top1, const float* __restrict__ top1p,
    const int* __restrict__ base, const float* __restrict__ mult0,
    int* __restrict__ kept_tok, float* __restrict__ kept_scale,
    int* __restrict__ slotmap)
{
    __shared__ int t1[64];
    const int tid = threadIdx.x;
    const int blk = blockIdx.x;
    const int gt  = blk * 64 + tid;
    const int e   = top1[gt];
    t1[tid] = e;
    __syncthreads();
    int r = 0;
    for (int i = 0; i < tid; ++i) r += (t1[i] == e) ? 1 : 0;
    const int rank = base[blk * EE + e] + r;
    int sm = -1;
    if (rank % CAP == 0) {
        const int slot = rank / CAP;            // kth kept token has rank k*CAP
        sm = e * KMAX + slot;
        kept_tok[sm] = gt;
        float sc = top1p[gt];
        if (gt == 0) sc *= mult0[0];            // fold fill-slot multiplicity
        kept_scale[sm] = sc;
    }
    slotmap[gt] = sm;
}

// ------------------------------------------------------------------- E1 -----
// h[e][s][f] = gelu(W1[e,f,:] . x[t_s] + b1[e,f]).
// grid EE*256, wave handles 4 f-rows; ONE butterfly per 4KB row.
// x kept in registers across the 4 rows (s-outer loop).
__global__ __launch_bounds__(256) void expert1_kernel(
    const float* __restrict__ x, const float* __restrict__ W1,
    const float* __restrict__ b1, const int* __restrict__ nkept,
    const int* __restrict__ kept_tok, float* __restrict__ h)
{
    const int e    = blockIdx.x >> 8;
    const int fblk = blockIdx.x & 255;
    const int ne   = nkept[e];
    if (ne == 0) return;
    const int wave = threadIdx.x >> 6;
    const int lane = threadIdx.x & 63;

    for (int s = 0; s < ne; ++s) {
        const int t = kept_tok[e * KMAX + s];
        const float4* xp = (const float4*)(x + (size_t)t * DD);
        const float4 x0 = xp[lane];
        const float4 x1 = xp[64 + lane];
        const float4 x2 = xp[128 + lane];
        const float4 x3 = xp[192 + lane];
        #pragma unroll
        for (int i = 0; i < 4; ++i) {
            const int f = fblk * 16 + wave * 4 + i;
            const float4* wrow = (const float4*)(W1 + ((size_t)e * FF + f) * DD);
            const float4 w0 = wrow[lane];
            const float4 w1 = wrow[64 + lane];
            const float4 w2 = wrow[128 + lane];
            const float4 w3 = wrow[192 + lane];
            float d = w0.x*x0.x + w0.y*x0.y + w0.z*x0.z + w0.w*x0.w
                    + w1.x*x1.x + w1.y*x1.y + w1.z*x1.z + w1.w*x1.w
                    + w2.x*x2.x + w2.y*x2.y + w2.z*x2.z + w2.w*x2.w
                    + w3.x*x3.x + w3.y*x3.y + w3.z*x3.z + w3.w*x3.w;
            d += __shfl_xor(d, 32);
            d += __shfl_xor(d, 16);
            d += __shfl_xor(d, 8);
            d += __shfl_xor(d, 4);
            d += __shfl_xor(d, 2);
            d += __shfl_xor(d, 1);
            if (lane == 0) {
                const float v = d + b1[e * FF + f];
                // exact gelu: 0.5*v*(1+erf(v/sqrt(2)))
                h[((size_t)e * KMAX + s) * FF + f] =
                    0.5f * v * (1.0f + erff(v * 0.70710678118654752440f));
            }
        }
    }
}

// ------------------------------------------------------------------- E2 -----
// eo[e][s][d] = scale * (W2[e,d,:] . h[e][s][:] + b2[e,d]).
// grid EE*64; block stages h[e,s,:] (16 KB) in LDS, wave handles 4 d-rows;
// ONE butterfly per 16KB W2 row (16 float4 loads in flight per lane).
__global__ __launch_bounds__(256) void expert2_kernel(
    const float* __restrict__ h, const float* __restrict__ W2,
    const float* __restrict__ b2, const int* __restrict__ nkept,
    const float* __restrict__ kept_scale, float* __restrict__ eo)
{
    const int e    = blockIdx.x >> 6;
    const int dblk = blockIdx.x & 63;
    const int ne   = nkept[e];
    if (ne == 0) return;
    const int wave = threadIdx.x >> 6;
    const int lane = threadIdx.x & 63;
    const int tid  = threadIdx.x;

    __shared__ float hs[FF];   // 16 KB

    for (int s = 0; s < ne; ++s) {
        if (s > 0) __syncthreads();   // drain readers before restaging
        // stage h row: 1024 float4, 4 per thread
        const float4* hp = (const float4*)(h + ((size_t)e * KMAX + s) * FF);
        #pragma unroll
        for (int k = 0; k < 4; ++k)
            ((float4*)hs)[tid + k * 256] = hp[tid + k * 256];
        __syncthreads();

        const float sc = kept_scale[e * KMAX + s];
        #pragma unroll
        for (int i = 0; i < 4; ++i) {
            const int d = dblk * 16 + wave * 4 + i;
            const float4* wrow = (const float4*)(W2 + ((size_t)e * DD + d) * FF);
            float acc = 0.0f;
            #pragma unroll
            for (int k = 0; k < 16; ++k) {
                const float4 w  = wrow[k * 64 + lane];
                const float4 hv = ((const float4*)hs)[k * 64 + lane];
                acc += w.x*hv.x + w.y*hv.y + w.z*hv.z + w.w*hv.w;
            }
            acc += __shfl_xor(acc, 32);
            acc += __shfl_xor(acc, 16);
            acc += __shfl_xor(acc, 8);
            acc += __shfl_xor(acc, 4);
            acc += __shfl_xor(acc, 2);
            acc += __shfl_xor(acc, 1);
            if (lane == 0)
                eo[((size_t)e * KMAX + s) * DD + d] = sc * (acc + b2[e * DD + d]);
        }
    }
}

// ---------------------------------------------------------------- expand ----
// single coalesced pass writing the full output (zeros or scattered eo rows;
// scale+bias already folded into eo by E2).
__global__ __launch_bounds__(256) void expand_kernel(
    const float* __restrict__ eo, const int* __restrict__ slotmap,
    float* __restrict__ out)
{
    const int nf4 = TOKENS * DD / 4;            // 4194304 float4
    int idx = blockIdx.x * 256 + threadIdx.x;
    const int stride = 4096 * 256;
    for (; idx < nf4; idx += stride) {
        const int t    = idx >> 8;              // 256 float4 per token
        const int slot = slotmap[t];
        float4 v = make_float4(0.0f, 0.0f, 0.0f, 0.0f);
        if (slot >= 0) v = ((const float4*)eo)[slot * 256 + (idx & 255)];
        ((float4*)out)[idx] = v;
    }
}

// -------------------------------------------------------------- launcher ----
extern "C" void kernel_launch(void* const* d_in, const int* in_sizes, int n_in,
                              void* d_out, int out_size, void* d_ws, size_t ws_size,
                              hipStream_t stream) {
    const float* x  = (const float*)d_in[0];
    const float* Wr = (const float*)d_in[1];
    const float* W1 = (const float*)d_in[2];
    const float* b1 = (const float*)d_in[3];
    const float* W2 = (const float*)d_in[4];
    const float* b2 = (const float*)d_in[5];
    float* out = (float*)d_out;

    char* p = (char*)d_ws;
    int*   top1       = (int*)p;    p += (size_t)TOKENS * 4;
    float* top1p      = (float*)p;  p += (size_t)TOKENS * 4;
    int*   slotmap    = (int*)p;    p += (size_t)TOKENS * 4;
    int*   blockhist  = (int*)p;    p += (size_t)NBLK * EE * 4;
    float* blockpsum  = (float*)p;  p += (size_t)NBLK * EE * 4;
    int*   base       = (int*)p;    p += (size_t)NBLK * EE * 4;
    int*   nkept      = (int*)p;    p += 256;
    float* mult0      = (float*)p;  p += 256;
    int*   kept_tok   = (int*)p;    p += 1024;   // EE*KMAX ints, padded
    float* kept_scale = (float*)p;  p += 1024;
    float* eo         = (float*)p;  p += (size_t)EE * KMAX * DD * 4;
    float* h          = (float*)p;  p += (size_t)EE * KMAX * FF * 4;
    (void)ws_size; (void)in_sizes; (void)n_in;

    router_kernel<<<NBLK, 256, 0, stream>>>(x, Wr, top1, top1p,
                                            blockhist, blockpsum);
    scan_kernel<<<1, 256, 0, stream>>>(blockhist, blockpsum, base, nkept,
                                       top1, mult0, out + (size_t)out_size - 1);
    keep_kernel<<<NBLK, 64, 0, stream>>>(top1, top1p, base, mult0,
                                         kept_tok, kept_scale, slotmap);
    expert1_kernel<<<EE * 256, 256, 0, stream>>>(x, W1, b1, nkept, kept_tok, h);
    expert2_kernel<<<EE * 64, 256, 0, stream>>>(h, W2, b2, nkept, kept_scale, eo);
    expand_kernel<<<4096, 256, 0, stream>>>(eo, slotmap, out);
}

// Round 4
// 664.842 us; speedup vs baseline: 1.1902x; 1.0150x over previous
//
#include <hip/hip_runtime.h>
#include <math.h>

// SwitchMOE: B=8,T=2048,D=1024,F=4096,E=16 ; capacity=1280, K=13
// R4: expert GEMVs restructured for loads-in-flight (Little's law).
//  - E2: grid EE*256 (was EE*64 = only 4 blocks/CU); wave-per-d-row, one
//    butterfly per 16KB W2 row; h read straight from L2 (256KB hot), no LDS,
//    no barriers -> 16 w + 16 h loads in flight per wave, 8 blocks/CU.
//  - E1: x re-read from L1 per row instead of 64-VGPR register cache ->
//    lower VGPR, 8 waves/SIMD.

#define TOKENS 16384
#define DD     1024
#define FF     4096
#define EE     16
#define CAP    1280
#define KMAX   13
#define NBLK   256   // router/keep blocks, 64 tokens each

// ---------------------------------------------------------------- router ----
// block = 256 thr (4 waves), 64 contiguous tokens per block.
// Each wave processes 4 tokens at a time: x in registers, Wr staged in LDS in
// 16KB chunks (j-loop), 64 accumulators, 6-level shfl_xor butterfly reduce.
__global__ __launch_bounds__(256) void router_kernel(
    const float* __restrict__ x, const float* __restrict__ Wr,
    int* __restrict__ top1, float* __restrict__ top1p,
    int* __restrict__ blockhist, float* __restrict__ blockpsum)
{
    __shared__ float wrj[EE * 256];   // 16 KB: Wr[:, j*256:(j+1)*256] as float4
    __shared__ float p_acc[EE];
    __shared__ int   hist[EE];

    const int tid  = threadIdx.x;
    const int wave = tid >> 6;
    const int lane = tid & 63;
    const int blk  = blockIdx.x;

    if (tid < EE) { p_acc[tid] = 0.0f; hist[tid] = 0; }

    for (int it = 0; it < 4; ++it) {
        const int tbase = blk * 64 + wave * 16 + it * 4;

        float4 xr[4][4];
        #pragma unroll
        for (int t = 0; t < 4; ++t) {
            const float4* xp = (const float4*)(x + (size_t)(tbase + t) * DD);
            #pragma unroll
            for (int j = 0; j < 4; ++j) xr[t][j] = xp[j * 64 + lane];
        }

        float acc[4][EE];
        #pragma unroll
        for (int t = 0; t < 4; ++t)
            #pragma unroll
            for (int e = 0; e < EE; ++e) acc[t][e] = 0.0f;

        for (int j = 0; j < 4; ++j) {
            __syncthreads();   // protect previous chunk readers
            #pragma unroll
            for (int k = 0; k < 4; ++k) {
                int i = tid + k * 256;            // float4 index in [0,1024)
                int e = i >> 6, c = i & 63;
                ((float4*)wrj)[i] = ((const float4*)Wr)[e * 256 + j * 64 + c];
            }
            __syncthreads();
            #pragma unroll
            for (int e = 0; e < EE; ++e) {
                float4 w = ((const float4*)(wrj + e * 256))[lane];
                #pragma unroll
                for (int t = 0; t < 4; ++t) {
                    acc[t][e] += xr[t][j].x * w.x + xr[t][j].y * w.y
                               + xr[t][j].z * w.z + xr[t][j].w * w.w;
                }
            }
        }

        // butterfly reduce: every lane ends with all totals
        #pragma unroll
        for (int t = 0; t < 4; ++t)
            #pragma unroll
            for (int e = 0; e < EE; ++e) {
                float v = acc[t][e];
                v += __shfl_xor(v, 32);
                v += __shfl_xor(v, 16);
                v += __shfl_xor(v, 8);
                v += __shfl_xor(v, 4);
                v += __shfl_xor(v, 2);
                v += __shfl_xor(v, 1);
                acc[t][e] = v;
            }

        if (lane < 4) {
            // select this lane's token logits without dynamic reg indexing
            float lg[EE];
            #pragma unroll
            for (int e = 0; e < EE; ++e) {
                float v = acc[3][e];
                if (lane == 2) v = acc[2][e];
                if (lane == 1) v = acc[1][e];
                if (lane == 0) v = acc[0][e];
                lg[e] = v;
            }
            const int gt = tbase + lane;
            float mx = lg[0]; int bi = 0;
            #pragma unroll
            for (int e = 1; e < EE; ++e)
                if (lg[e] > mx) { mx = lg[e]; bi = e; }   // first-max like argmax
            float pr[EE];
            float s = 0.0f;
            #pragma unroll
            for (int e = 0; e < EE; ++e) { pr[e] = expf(lg[e] - mx); s += pr[e]; }
            const float inv = 1.0f / s;
            top1[gt]  = bi;
            top1p[gt] = inv;                 // = exp(0)/s = max prob
            #pragma unroll
            for (int e = 0; e < EE; ++e) atomicAdd(&p_acc[e], pr[e] * inv);
            atomicAdd(&hist[bi], 1);
        }
    }
    __syncthreads();
    if (tid < EE) {
        blockhist[blk * EE + tid] = hist[tid];
        blockpsum[blk * EE + tid] = p_acc[tid];
    }
}

// ------------------------------------------------------------------ scan ----
// single block: exclusive prefix of blockhist over 256 blocks per expert,
// n_kept, token-0 fill multiplicity, lb_loss (reducing blockpsum).
__global__ __launch_bounds__(256) void scan_kernel(
    const int* __restrict__ blockhist, const float* __restrict__ blockpsum,
    int* __restrict__ base, int* __restrict__ nkept,
    const int* __restrict__ top1, float* __restrict__ mult0,
    float* __restrict__ lb_out)
{
    __shared__ int   hist_l[NBLK * EE];   // 16 KB
    __shared__ int   gsum[EE * 16];
    __shared__ float fps[EE * 16];
    __shared__ float fp[EE];
    __shared__ int   nk_l[EE];

    const int tid = threadIdx.x;
    for (int i = tid; i < NBLK * EE; i += 256) hist_l[i] = blockhist[i];
    __syncthreads();

    const int e = tid >> 4, g = tid & 15;   // 16 experts x 16 groups of 16 blocks
    int s = 0;
    float sp = 0.0f;
    for (int b = g * 16; b < g * 16 + 16; ++b) {
        s  += hist_l[b * EE + e];
        sp += blockpsum[b * EE + e];
    }
    gsum[e * 16 + g] = s;
    fps[e * 16 + g]  = sp;
    __syncthreads();

    int pre = 0;
    for (int g2 = 0; g2 < g; ++g2) pre += gsum[e * 16 + g2];
    int run = pre;
    for (int b = g * 16; b < g * 16 + 16; ++b) {
        base[b * EE + e] = run;
        run += hist_l[b * EE + e];
    }
    if (g == 15) {
        const int c = run;                      // total count for expert e
        const int nk = (c > 0) ? ((c - 1) / CAP + 1) : 0;
        nkept[e] = nk;
        nk_l[e]  = nk;
        float ps = 0.0f;
        for (int g2 = 0; g2 < 16; ++g2) ps += fps[e * 16 + g2];
        fp[e] = ((float)c / (float)TOKENS) * (ps / (float)TOKENS);
    }
    __syncthreads();
    if (tid == 0) {
        const int e0 = top1[0];
        mult0[0] = (float)(1 + KMAX - nk_l[e0]);  // token-0 fill multiplicity
        float sum = 0.0f;
        for (int i = 0; i < EE; ++i) sum += fp[i];
        lb_out[0] = (float)EE * sum * 0.01f;
    }
}

// ------------------------------------------------------------------ keep ----
// per 64-token block: within-block rank recount -> kept-slot list + full
// slotmap write (no memset needed).
__global__ __launch_bounds__(64) void keep_kernel(
    const int* __restrict__ top1, const float* __restrict__ top1p,
    const int* __restrict__ base, const float* __restrict__ mult0,
    int* __restrict__ kept_tok, float* __restrict__ kept_scale,
    int* __restrict__ slotmap)
{
    __shared__ int t1[64];
    const int tid = threadIdx.x;
    const int blk = blockIdx.x;
    const int gt  = blk * 64 + tid;
    const int e   = top1[gt];
    t1[tid] = e;
    __syncthreads();
    int r = 0;
    for (int i = 0; i < tid; ++i) r += (t1[i] == e) ? 1 : 0;
    const int rank = base[blk * EE + e] + r;
    int sm = -1;
    if (rank % CAP == 0) {
        const int slot = rank / CAP;            // kth kept token has rank k*CAP
        sm = e * KMAX + slot;
        kept_tok[sm] = gt;
        float sc = top1p[gt];
        if (gt == 0) sc *= mult0[0];            // fold fill-slot multiplicity
        kept_scale[sm] = sc;
    }
    slotmap[gt] = sm;
}

// ------------------------------------------------------------------- E1 -----
// h[e][s][f] = gelu(W1[e,f,:] . x[t_s] + b1[e,f]).
// grid EE*256, wave handles 4 f-rows; x re-read per row (L1-hot: same 4KB
// row for all 4 waves of the block) -> low VGPR, 8 waves/SIMD, compiler free
// to pipeline row i+1's loads over row i's reduce.
__global__ __launch_bounds__(256) void expert1_kernel(
    const float* __restrict__ x, const float* __restrict__ W1,
    const float* __restrict__ b1, const int* __restrict__ nkept,
    const int* __restrict__ kept_tok, float* __restrict__ h)
{
    const int e    = blockIdx.x >> 8;
    const int fblk = blockIdx.x & 255;
    const int ne   = nkept[e];
    if (ne == 0) return;
    const int wave = threadIdx.x >> 6;
    const int lane = threadIdx.x & 63;

    for (int s = 0; s < ne; ++s) {
        const int t = kept_tok[e * KMAX + s];
        const float4* xp = (const float4*)(x + (size_t)t * DD);
        #pragma unroll
        for (int i = 0; i < 4; ++i) {
            const int f = fblk * 16 + wave * 4 + i;
            const float4* wrow = (const float4*)(W1 + ((size_t)e * FF + f) * DD);
            float d = 0.0f;
            #pragma unroll
            for (int k = 0; k < 4; ++k) {
                const float4 w  = wrow[k * 64 + lane];
                const float4 xv = xp[k * 64 + lane];
                d += w.x*xv.x + w.y*xv.y + w.z*xv.z + w.w*xv.w;
            }
            d += __shfl_xor(d, 32);
            d += __shfl_xor(d, 16);
            d += __shfl_xor(d, 8);
            d += __shfl_xor(d, 4);
            d += __shfl_xor(d, 2);
            d += __shfl_xor(d, 1);
            if (lane == 0) {
                const float v = d + b1[e * FF + f];
                // exact gelu: 0.5*v*(1+erf(v/sqrt(2)))
                h[((size_t)e * KMAX + s) * FF + f] =
                    0.5f * v * (1.0f + erff(v * 0.70710678118654752440f));
            }
        }
    }
}

// ------------------------------------------------------------------- E2 -----
// eo[e][s][d] = scale * (W2[e,d,:] . h[e][s][:] + b2[e,d]).
// grid EE*256 (8 blocks/CU co-resident), wave-per-d-row: 16 w (HBM) + 16 h
// (L2-hot, h totals 256KB) float4 loads in flight, ONE butterfly per 16KB.
// No LDS, no barriers -> nothing drains the load queue.
__global__ __launch_bounds__(256) void expert2_kernel(
    const float* __restrict__ h, const float* __restrict__ W2,
    const float* __restrict__ b2, const int* __restrict__ nkept,
    const float* __restrict__ kept_scale, float* __restrict__ eo)
{
    const int e    = blockIdx.x >> 8;
    const int dblk = blockIdx.x & 255;
    const int ne   = nkept[e];
    if (ne == 0) return;
    const int wave = threadIdx.x >> 6;
    const int lane = threadIdx.x & 63;
    const int d    = dblk * 4 + wave;

    const float4* wrow = (const float4*)(W2 + ((size_t)e * DD + d) * FF);
    for (int s = 0; s < ne; ++s) {
        const float4* hp = (const float4*)(h + ((size_t)e * KMAX + s) * FF);
        float acc = 0.0f;
        #pragma unroll
        for (int k = 0; k < 16; ++k) {
            const float4 w  = wrow[k * 64 + lane];
            const float4 hv = hp[k * 64 + lane];
            acc += w.x*hv.x + w.y*hv.y + w.z*hv.z + w.w*hv.w;
        }
        acc += __shfl_xor(acc, 32);
        acc += __shfl_xor(acc, 16);
        acc += __shfl_xor(acc, 8);
        acc += __shfl_xor(acc, 4);
        acc += __shfl_xor(acc, 2);
        acc += __shfl_xor(acc, 1);
        if (lane == 0) {
            const float sc = kept_scale[e * KMAX + s];
            eo[((size_t)e * KMAX + s) * DD + d] = sc * (acc + b2[e * DD + d]);
        }
    }
}

// ---------------------------------------------------------------- expand ----
// single coalesced pass writing the full output (zeros or scattered eo rows;
// scale+bias already folded into eo by E2).
__global__ __launch_bounds__(256) void expand_kernel(
    const float* __restrict__ eo, const int* __restrict__ slotmap,
    float* __restrict__ out)
{
    const int nf4 = TOKENS * DD / 4;            // 4194304 float4
    int idx = blockIdx.x * 256 + threadIdx.x;
    const int stride = 4096 * 256;
    for (; idx < nf4; idx += stride) {
        const int t    = idx >> 8;              // 256 float4 per token
        const int slot = slotmap[t];
        float4 v = make_float4(0.0f, 0.0f, 0.0f, 0.0f);
        if (slot >= 0) v = ((const float4*)eo)[slot * 256 + (idx & 255)];
        ((float4*)out)[idx] = v;
    }
}

// -------------------------------------------------------------- launcher ----
extern "C" void kernel_launch(void* const* d_in, const int* in_sizes, int n_in,
                              void* d_out, int out_size, void* d_ws, size_t ws_size,
                              hipStream_t stream) {
    const float* x  = (const float*)d_in[0];
    const float* Wr = (const float*)d_in[1];
    const float* W1 = (const float*)d_in[2];
    const float* b1 = (const float*)d_in[3];
    const float* W2 = (const float*)d_in[4];
    const float* b2 = (const float*)d_in[5];
    float* out = (float*)d_out;

    char* p = (char*)d_ws;
    int*   top1       = (int*)p;    p += (size_t)TOKENS * 4;
    float* top1p      = (float*)p;  p += (size_t)TOKENS * 4;
    int*   slotmap    = (int*)p;    p += (size_t)TOKENS * 4;
    int*   blockhist  = (int*)p;    p += (size_t)NBLK * EE * 4;
    float* blockpsum  = (float*)p;  p += (size_t)NBLK * EE * 4;
    int*   base       = (int*)p;    p += (size_t)NBLK * EE * 4;
    int*   nkept      = (int*)p;    p += 256;
    float* mult0      = (float*)p;  p += 256;
    int*   kept_tok   = (int*)p;    p += 1024;   // EE*KMAX ints, padded
    float* kept_scale = (float*)p;  p += 1024;
    float* eo         = (float*)p;  p += (size_t)EE * KMAX * DD * 4;
    float* h          = (float*)p;  p += (size_t)EE * KMAX * FF * 4;
    (void)ws_size; (void)in_sizes; (void)n_in;

    router_kernel<<<NBLK, 256, 0, stream>>>(x, Wr, top1, top1p,
                                            blockhist, blockpsum);
    scan_kernel<<<1, 256, 0, stream>>>(blockhist, blockpsum, base, nkept,
                                       top1, mult0, out + (size_t)out_size - 1);
    keep_kernel<<<NBLK, 64, 0, stream>>>(top1, top1p, base, mult0,
                                         kept_tok, kept_scale, slotmap);
    expert1_kernel<<<EE * 256, 256, 0, stream>>>(x, W1, b1, nkept, kept_tok, h);
    expert2_kernel<<<EE * 256, 256, 0, stream>>>(h, W2, b2, nkept, kept_scale, eo);
    expand_kernel<<<4096, 256, 0, stream>>>(eo, slotmap, out);
}